// Round 11
// baseline (212.624 us; speedup 1.0000x reference)
//
#include <hip/hip_runtime.h>
#include <hip/hip_bf16.h>
#include <stdint.h>

#define DMODEL 256
#define BATCH  16
#define MEL    2048
#define SRC    512

typedef __attribute__((ext_vector_type(8))) short bf16x8;
typedef __attribute__((ext_vector_type(4))) short short4v;
typedef __attribute__((ext_vector_type(4))) float f32x4;

__device__ inline short f2bf(float f) {
    union { float f; uint32_t u; } c{f};
    uint32_t u = c.u;
    u += 0x7FFFu + ((u >> 16) & 1u);   // RNE
    return (short)(u >> 16);
}

__device__ inline bf16x8 cvt8(const float* p) {
    const f32x4* q = reinterpret_cast<const f32x4*>(p);
    f32x4 a = q[0], b = q[1];
    bf16x8 r;
    r[0] = f2bf(a[0]); r[1] = f2bf(a[1]); r[2] = f2bf(a[2]); r[3] = f2bf(a[3]);
    r[4] = f2bf(b[0]); r[5] = f2bf(b[1]); r[6] = f2bf(b[2]); r[7] = f2bf(b[3]);
    return r;
}

// ============================================================================
// proj_all: q/k/vt as 128(M)x64(N)x256 tile-units, f32 in, bf16 out.
// 4 waves as 2x2, wave-tile 64x32 -> acc 4x2 (32 AGPR). ~100 regs total ->
// 16 waves/CU, 4 blocks/CU (LDS 27.6 KB).
// Decode (XCD-affine, mel-stripe-grouped):
//   u < 2048: kv-unit. xcd=u&7; t=u>>3; kind=t&7; sg=t>>3; stripe=(sg<<3)|xcd
//     (128 mel rows, L2-resident per XCD). kind<4: k-tile (col-block kind);
//     kind>=4: vt-tile (Wv-half (kind-4)>>1, mel-64-sub (kind-4)&1).
//   u >= 2048: q-unit. xcd=v&7; mt=8*xcd+(qj>>2) (batch affinity), nt=qj&3.
// ============================================================================
__global__ __launch_bounds__(256, 4)
void proj_all_kernel(const float* __restrict__ mel, const float* __restrict__ text,
                     const float* __restrict__ Wq, const float* __restrict__ Wk,
                     const float* __restrict__ Wv,
                     short* __restrict__ qbf, short* __restrict__ kbf,
                     short* __restrict__ vt) {
    __shared__ char SMEM[27648];                 // As[128][72] | Bs[64][72] shorts
    short* As = (short*)SMEM;
    short* Bs = (short*)SMEM + 128 * 72;

    const int tid = threadIdx.x;
    const int lane = tid & 63, w = tid >> 6;
    const int lr = lane & 15, lk = lane >> 4;
    const int wr = w >> 1, wc = w & 1;

    const int u = blockIdx.x;
    const float *Af, *Bf; short* C; int ldc;
    size_t aro, bro;
    if (u < 2048) {
        const int xcd = u & 7, t = u >> 3;
        const int kind = t & 7, sg = t >> 3;
        const int stripe = (sg << 3) | xcd;      // 0..255
        const int b = stripe >> 4;
        const size_t mr0 = (size_t)(stripe & 15) * 128;
        if (kind < 4) {          // k-tile
            aro = (size_t)b * MEL + mr0;
            bro = (size_t)kind * 64;
            Af = mel; Bf = Wk; ldc = DMODEL;
            C = kbf + aro * DMODEL + bro;
        } else {                 // vt-tile
            const int kk = kind - 4;
            aro = (size_t)(kk >> 1) * 128;
            bro = (size_t)b * MEL + mr0 + (size_t)(kk & 1) * 64;
            Af = Wv; Bf = mel; ldc = MEL;
            C = vt + (size_t)b * DMODEL * MEL + aro * MEL + mr0 + (size_t)(kk & 1) * 64;
        }
    } else {
        const int v = u - 2048;
        const int xcd = v & 7, qj = v >> 3;
        const int mt = 8 * xcd + (qj >> 2), nt = qj & 3;
        aro = (size_t)mt * 128;
        bro = (size_t)nt * 64;
        Af = text; Bf = Wq; ldc = DMODEL;
        C = qbf + aro * DMODEL + bro;
    }

    bf16x8 sA[4], sB[2];
    auto STAGE = [&](int kt) {
#pragma unroll
        for (int i = 0; i < 4; ++i) {
            int idx = i * 256 + tid;
            int row = idx >> 3, c8 = (idx & 7) * 8;
            sA[i] = cvt8(Af + (aro + row) * 256 + kt * 64 + c8);
        }
#pragma unroll
        for (int i = 0; i < 2; ++i) {
            int idx = i * 256 + tid;
            int row = idx >> 3, c8 = (idx & 7) * 8;
            sB[i] = cvt8(Bf + (bro + row) * 256 + kt * 64 + c8);
        }
    };

    STAGE(0);
    f32x4 acc[4][2];
#pragma unroll
    for (int m = 0; m < 4; ++m)
#pragma unroll
        for (int n = 0; n < 2; ++n) acc[m][n] = (f32x4){0.f, 0.f, 0.f, 0.f};

    for (int kt = 0; kt < 4; ++kt) {
        __syncthreads();
#pragma unroll
        for (int i = 0; i < 4; ++i) {
            int idx = i * 256 + tid;
            *(bf16x8*)&As[(idx >> 3) * 72 + (idx & 7) * 8] = sA[i];
        }
#pragma unroll
        for (int i = 0; i < 2; ++i) {
            int idx = i * 256 + tid;
            *(bf16x8*)&Bs[(idx >> 3) * 72 + (idx & 7) * 8] = sB[i];
        }
        __syncthreads();
        if (kt < 3) STAGE(kt + 1);
#pragma unroll
        for (int kt2 = 0; kt2 < 2; ++kt2) {
            bf16x8 af[4], bfr[2];
#pragma unroll
            for (int m = 0; m < 4; ++m)
                af[m] = *(const bf16x8*)&As[(64 * wr + 16 * m + lr) * 72 + kt2 * 32 + 8 * lk];
#pragma unroll
            for (int n = 0; n < 2; ++n)
                bfr[n] = *(const bf16x8*)&Bs[(32 * wc + 16 * n + lr) * 72 + kt2 * 32 + 8 * lk];
#pragma unroll
            for (int m = 0; m < 4; ++m)
#pragma unroll
                for (int n = 0; n < 2; ++n)
                    acc[m][n] = __builtin_amdgcn_mfma_f32_16x16x32_bf16(af[m], bfr[n], acc[m][n], 0, 0, 0);
        }
    }

    // C epilogue: stage bf16 tile [128][72] in LDS, coalesced row writes
    __syncthreads();
    short* Cs = (short*)SMEM;
#pragma unroll
    for (int m = 0; m < 4; ++m)
#pragma unroll
        for (int n = 0; n < 2; ++n)
#pragma unroll
            for (int r = 0; r < 4; ++r)
                Cs[(64 * wr + 16 * m + 4 * lk + r) * 72 + 32 * wc + 16 * n + lr] =
                    f2bf(acc[m][n][r]);
    __syncthreads();
#pragma unroll
    for (int i = 0; i < 4; ++i) {
        int idx = i * 256 + tid;
        int row = idx >> 3, c8 = (idx & 7) * 8;
        *(bf16x8*)&C[(size_t)row * ldc + c8] = *(const bf16x8*)&Cs[row * 72 + c8];
    }
}

// ============================================================================
// sgemm: S[b] = q[b] @ k[b]^T / 16, mel-masked -> attn f32; per-(row,64-col)
// softmax partials. Tile 128x64, wave-tile 64x32, grid 2048 XCD-affine.
// ============================================================================
__global__ __launch_bounds__(256, 4)
void sgemm_kernel(const short* __restrict__ qbf, const short* __restrict__ kbf,
                  const int* __restrict__ mel_mask,
                  float* __restrict__ attn,
                  float* __restrict__ pmax, float* __restrict__ psum) {
    __shared__ char SMEM[27648];
    short* As = (short*)SMEM;
    short* Bs = (short*)SMEM + 128 * 72;

    const int tid = threadIdx.x;
    const int lane = tid & 63, w = tid >> 6;
    const int lr = lane & 15, lk = lane >> 4;
    const int wr = w >> 1, wc = w & 1;

    const int bid = blockIdx.x;
    const int xcd = bid & 7, j = bid >> 3;       // j 0..255
    const int z = 2 * xcd + (j >> 7);
    const int t = j & 127;
    const int x = t & 3, y = t >> 2;             // x: M-tile(128), y: N-tile(64)

    const short* A = qbf + (size_t)z * SRC * DMODEL + (size_t)x * 128 * DMODEL;
    const short* B = kbf + (size_t)z * MEL * DMODEL + (size_t)y * 64 * DMODEL;
    float* Cw = attn + (size_t)z * SRC * MEL + (size_t)x * 128 * MEL + (size_t)y * 64;

    bf16x8 sA[4], sB[2];
    auto STAGE = [&](int kt) {
#pragma unroll
        for (int i = 0; i < 4; ++i) {
            int idx = i * 256 + tid;
            sA[i] = *(const bf16x8*)(A + (size_t)(idx >> 3) * DMODEL + kt * 64 + (idx & 7) * 8);
        }
#pragma unroll
        for (int i = 0; i < 2; ++i) {
            int idx = i * 256 + tid;
            sB[i] = *(const bf16x8*)(B + (size_t)(idx >> 3) * DMODEL + kt * 64 + (idx & 7) * 8);
        }
    };

    STAGE(0);
    f32x4 acc[4][2];
#pragma unroll
    for (int m = 0; m < 4; ++m)
#pragma unroll
        for (int n = 0; n < 2; ++n) acc[m][n] = (f32x4){0.f, 0.f, 0.f, 0.f};

    for (int kt = 0; kt < 4; ++kt) {
        __syncthreads();
#pragma unroll
        for (int i = 0; i < 4; ++i) {
            int idx = i * 256 + tid;
            *(bf16x8*)&As[(idx >> 3) * 72 + (idx & 7) * 8] = sA[i];
        }
#pragma unroll
        for (int i = 0; i < 2; ++i) {
            int idx = i * 256 + tid;
            *(bf16x8*)&Bs[(idx >> 3) * 72 + (idx & 7) * 8] = sB[i];
        }
        __syncthreads();
        if (kt < 3) STAGE(kt + 1);
#pragma unroll
        for (int kt2 = 0; kt2 < 2; ++kt2) {
            bf16x8 af[4], bfr[2];
#pragma unroll
            for (int m = 0; m < 4; ++m)
                af[m] = *(const bf16x8*)&As[(64 * wr + 16 * m + lr) * 72 + kt2 * 32 + 8 * lk];
#pragma unroll
            for (int n = 0; n < 2; ++n)
                bfr[n] = *(const bf16x8*)&Bs[(32 * wc + 16 * n + lr) * 72 + kt2 * 32 + 8 * lk];
#pragma unroll
            for (int m = 0; m < 4; ++m)
#pragma unroll
                for (int n = 0; n < 2; ++n)
                    acc[m][n] = __builtin_amdgcn_mfma_f32_16x16x32_bf16(af[m], bfr[n], acc[m][n], 0, 0, 0);
        }
    }

    bool msk[2];
#pragma unroll
    for (int n = 0; n < 2; ++n)
        msk[n] = mel_mask[z * MEL + y * 64 + 32 * wc + 16 * n + lr] != 0;

    // epilogue: two 64-row halves via LDS [64][68] f32; masked+scaled; partials
    __syncthreads();
    float* Cs = (float*)SMEM;
#pragma unroll
    for (int half = 0; half < 2; ++half) {
        if (wr == half) {
#pragma unroll
            for (int m = 0; m < 4; ++m)
#pragma unroll
                for (int n = 0; n < 2; ++n)
#pragma unroll
                    for (int r = 0; r < 4; ++r)
                        Cs[(16 * m + 4 * lk + r) * 68 + 32 * wc + 16 * n + lr] =
                            msk[n] ? -1e30f : acc[m][n][r] * 0.0625f;
        }
        __syncthreads();
#pragma unroll
        for (int i = 0; i < 4; ++i) {
            int idx = i * 256 + tid;
            int row = idx >> 4, c4 = (idx & 15) * 4;
            *(f32x4*)&Cw[(size_t)(half * 64 + row) * MEL + c4] = *(const f32x4*)&Cs[row * 68 + c4];
        }
        {   // partials: 4 threads/row, 16 cols each
            const int rrow = tid >> 2, seg = tid & 3;
            const f32x4* crow = (const f32x4*)(Cs + rrow * 68 + seg * 16);
            float m8 = -3.0e38f;
#pragma unroll
            for (int jj = 0; jj < 4; ++jj) {
                f32x4 vv = crow[jj];
#pragma unroll
                for (int e = 0; e < 4; ++e) m8 = fmaxf(m8, vv[e]);
            }
            m8 = fmaxf(m8, __shfl_xor(m8, 1));
            m8 = fmaxf(m8, __shfl_xor(m8, 2));
            float s8 = 0.f;
#pragma unroll
            for (int jj = 0; jj < 4; ++jj) {
                f32x4 vv = crow[jj];
#pragma unroll
                for (int e = 0; e < 4; ++e) s8 += __expf(vv[e] - m8);
            }
            s8 += __shfl_xor(s8, 1);
            s8 += __shfl_xor(s8, 2);
            if (seg == 0) {
                int grow = z * SRC + x * 128 + half * 64 + rrow;
                pmax[y * 8192 + grow] = m8;
                psum[y * 8192 + grow] = s8;
            }
        }
        __syncthreads();
    }
}

// ---- combine 32 partials per row -> M, inv=1/Z (src-masked) ----
__global__ __launch_bounds__(512)
void rowred_kernel(const float* __restrict__ pmax, const float* __restrict__ psum,
                   const int* __restrict__ src_mask,
                   float* __restrict__ Mrow, float* __restrict__ Minv) {
    const int row = blockIdx.x * 512 + threadIdx.x;    // 0..8191
    float M = -3.0e38f;
#pragma unroll
    for (int i = 0; i < 32; ++i) M = fmaxf(M, pmax[i * 8192 + row]);
    float Z = 0.f;
#pragma unroll
    for (int i = 0; i < 32; ++i)
        Z += psum[i * 8192 + row] * __expf(pmax[i * 8192 + row] - M);
    Mrow[row] = M;
    Minv[row] = (src_mask[row] || !(Z > 0.f)) ? 0.f : 1.f / Z;
}

// ============================================================================
// pv_ln: softmax-apply fused into A-stage (attn f32 written in-place),
// PV GEMM + fused LN. BM=16, BN=256, BK=64, 512 thr (8 waves, 32 cols each).
// grid 512, XCD-affine -> exactly 2 blocks/CU, fully resident.
// ============================================================================
__global__ __launch_bounds__(512, 4)
void pv_ln_kernel(float* __restrict__ attn, const short* __restrict__ vt,
                  const float* __restrict__ gamma, const float* __restrict__ beta,
                  const float* __restrict__ Mrow, const float* __restrict__ Minv,
                  float* __restrict__ out) {
    __shared__ char SMEM[39168];
    short* As = (short*)SMEM;                    // [16][72] shorts = 2304 B
    short* Bs = (short*)(SMEM + 2304);           // [256][72] shorts = 36864 B
    float* red = (float*)SMEM;                   // aliases As after K-loop
    float* Ost = (float*)(SMEM + 2304);          // [16][260] f32, aliases Bs

    const int tid = threadIdx.x;
    const int lane = tid & 63, w = tid >> 6;
    const int lr = lane & 15, lk = lane >> 4;

    const int bid = blockIdx.x;
    const int xcd = bid & 7, j = bid >> 3;       // j 0..63
    const int b = 2 * xcd + (j >> 5);
    const int mt = j & 31;
    const size_t row0 = (size_t)mt * 16;

    float* A = attn + (size_t)b * SRC * MEL + row0 * MEL;
    const short* Bv = vt + (size_t)b * DMODEL * MEL;

    float gm[2], bt[2];
#pragma unroll
    for (int n = 0; n < 2; ++n) {
        gm[n] = gamma[32 * w + 16 * n + lr];
        bt[n] = beta[32 * w + 16 * n + lr];
    }

    const int a_row = (tid & 255) >> 4, a_c4 = (tid & 15) * 4;
    float Mr = 0.f, Iv = 0.f;
    if (tid < 256) {
        Mr = Mrow[(size_t)b * SRC + row0 + a_row];
        Iv = Minv[(size_t)b * SRC + row0 + a_row];
    }

    f32x4 sAv; bf16x8 sB[4];
    auto STAGE = [&](int kt) {
        if (tid < 256)
            sAv = *(const f32x4*)(A + (size_t)a_row * MEL + kt * 64 + a_c4);
#pragma unroll
        for (int i = 0; i < 4; ++i) {
            int idx = i * 512 + tid;
            sB[i] = *(const bf16x8*)(Bv + (size_t)(idx >> 3) * MEL + kt * 64 + (idx & 7) * 8);
        }
    };

    STAGE(0);
    f32x4 acc[2];
    acc[0] = (f32x4){0.f, 0.f, 0.f, 0.f};
    acc[1] = (f32x4){0.f, 0.f, 0.f, 0.f};

    for (int kt = 0; kt < MEL / 64; ++kt) {
        __syncthreads();
        if (tid < 256) {
            f32x4 p;
#pragma unroll
            for (int e = 0; e < 4; ++e) p[e] = __expf(sAv[e] - Mr) * Iv;
            *(f32x4*)(A + (size_t)a_row * MEL + kt * 64 + a_c4) = p;
            short4v a4 = { f2bf(p[0]), f2bf(p[1]), f2bf(p[2]), f2bf(p[3]) };
            *(short4v*)&As[a_row * 72 + a_c4] = a4;
        }
#pragma unroll
        for (int i = 0; i < 4; ++i) {
            int idx = i * 512 + tid;
            *(bf16x8*)&Bs[(idx >> 3) * 72 + (idx & 7) * 8] = sB[i];
        }
        __syncthreads();
        if (kt + 1 < MEL / 64) STAGE(kt + 1);
#pragma unroll
        for (int kt2 = 0; kt2 < 2; ++kt2) {
            bf16x8 af = *(const bf16x8*)&As[lr * 72 + kt2 * 32 + 8 * lk];
#pragma unroll
            for (int n = 0; n < 2; ++n) {
                bf16x8 bfr = *(const bf16x8*)&Bs[(32 * w + 16 * n + lr) * 72 + kt2 * 32 + 8 * lk];
                acc[n] = __builtin_amdgcn_mfma_f32_16x16x32_bf16(af, bfr, acc[n], 0, 0, 0);
            }
        }
    }

    // LN: thread holds rows {4lk+r}, cols {32w+16n+lr}
    float s1[4] = {0.f, 0.f, 0.f, 0.f}, s2[4] = {0.f, 0.f, 0.f, 0.f};
#pragma unroll
    for (int n = 0; n < 2; ++n)
#pragma unroll
        for (int r = 0; r < 4; ++r) {
            s1[r] += acc[n][r];
            s2[r] += acc[n][r] * acc[n][r];
        }
#pragma unroll
    for (int off = 8; off; off >>= 1)
#pragma unroll
        for (int r = 0; r < 4; ++r) {
            s1[r] += __shfl_xor(s1[r], off);
            s2[r] += __shfl_xor(s2[r], off);
        }
    __syncthreads();                 // K-loop reads of As done; red aliases As
    if (lr == 0) {
#pragma unroll
        for (int r = 0; r < 4; ++r) {
            red[(4 * lk + r) * 8 + w] = s1[r];
            red[128 + (4 * lk + r) * 8 + w] = s2[r];
        }
    }
    __syncthreads();
    float mu[4], rsig[4];
#pragma unroll
    for (int r = 0; r < 4; ++r) {
        const int rowi = 4 * lk + r;
        float S1 = 0.f, S2 = 0.f;
#pragma unroll
        for (int ww = 0; ww < 8; ++ww) {
            S1 += red[rowi * 8 + ww];
            S2 += red[128 + rowi * 8 + ww];
        }
        mu[r] = S1 * (1.f / DMODEL);
        rsig[r] = rsqrtf(S2 * (1.f / DMODEL) - mu[r] * mu[r] + 1e-5f);
    }
    __syncthreads();                 // before overwriting Bs with Ost
#pragma unroll
    for (int n = 0; n < 2; ++n)
#pragma unroll
        for (int r = 0; r < 4; ++r)
            Ost[(4 * lk + r) * 260 + 32 * w + 16 * n + lr] =
                (acc[n][r] - mu[r]) * rsig[r] * gm[n] + bt[n];
    __syncthreads();
#pragma unroll
    for (int i = 0; i < 2; ++i) {
        int idx = i * 512 + tid;
        int row = idx >> 6, c4 = (idx & 63) * 4;
        *(f32x4*)&out[((size_t)b * SRC + row0 + row) * DMODEL + c4] =
            *(const f32x4*)&Ost[row * 260 + c4];
    }
}

extern "C" void kernel_launch(void* const* d_in, const int* in_sizes, int n_in,
                              void* d_out, int out_size, void* d_ws, size_t ws_size,
                              hipStream_t stream) {
    const float* mel      = (const float*)d_in[0];
    const float* text     = (const float*)d_in[1];
    const int*   mel_mask = (const int*)d_in[2];
    const int*   src_mask = (const int*)d_in[3];
    const float* Wq       = (const float*)d_in[4];
    const float* Wk       = (const float*)d_in[5];
    const float* Wv       = (const float*)d_in[6];
    const float* gamma    = (const float*)d_in[7];
    const float* beta     = (const float*)d_in[8];

    float* out  = (float*)d_out;
    float* attn = out + (size_t)BATCH * SRC * DMODEL;   // [16][512][2048] f32

    short* qbf = (short*)d_ws;                          // [8192][256] bf16
    short* kbf = qbf + (size_t)BATCH * SRC * DMODEL;    // [32768][256] bf16
    short* vt  = kbf + (size_t)BATCH * MEL * DMODEL;    // [16][256][2048] bf16
    float* pmax = (float*)(vt + (size_t)BATCH * DMODEL * MEL);  // [32][8192]
    float* psum = pmax + 32 * 8192;                             // [32][8192]
    float* Mrow = psum + 32 * 8192;                             // [8192]
    float* Minv = Mrow + 8192;                                  // [8192]

    proj_all_kernel<<<2304, 256, 0, stream>>>(mel, text, Wq, Wk, Wv, qbf, kbf, vt);
    sgemm_kernel<<<2048, 256, 0, stream>>>(qbf, kbf, mel_mask, attn, pmax, psum);
    rowred_kernel<<<16, 512, 0, stream>>>(pmax, psum, src_mask, Mrow, Minv);
    pv_ln_kernel<<<512, 512, 0, stream>>>(attn, vt, gamma, beta, Mrow, Minv, out);
}